// Round 16
// baseline (451.551 us; speedup 1.0000x reference)
//
#include <hip/hip_runtime.h>
#include <hip/hip_fp8.h>

#define F_IN 500
#define HH 32
#define DD 64
#define LN_EPS 1e-6f
#define QCAP 100000     // slots per (cohort, writer-class) queue
#define SPAN 4096       // edges per wave in binq
#define FWN 448         // fillq window (nodes)
#define FCAP 16384      // fillq LDS entry capacity (64 KB)
#define CW 12500        // cohort width (N/8)

typedef float f32x4 __attribute__((ext_vector_type(4)));
typedef float f32x2 __attribute__((ext_vector_type(2)));
typedef _Float16 f16x8 __attribute__((ext_vector_type(8)));
typedef _Float16 h16;

__device__ __forceinline__ unsigned char f2fp8(float x) {
    __hip_fp8_e4m3 t(x);
    return (unsigned char)t.__x;
}
__device__ __forceinline__ float fp82f(unsigned char b) {
    __hip_fp8_e4m3 t;
    t.__x = (__hip_fp8_storage_t)b;
    return (float)t;
}

// ---------------------------------------------------------------------------
// prep: W1T f16 [32 j][512 k] (zero-padded k>=500), W2T f16 [64 d][32 j]
// ---------------------------------------------------------------------------
__global__ __launch_bounds__(256)
void prep_k(const float* __restrict__ W1, const float* __restrict__ W2,
            h16* __restrict__ w1t, h16* __restrict__ w2t)
{
    int i = blockIdx.x * 256 + threadIdx.x;
    if (i < 32 * 512) {
        int j = i >> 9, k = i & 511;
        w1t[i] = (k < F_IN) ? (h16)W1[k * HH + j] : (h16)0.f;
    }
    int i2 = i - 32 * 512;
    if (i2 >= 0 && i2 < 64 * 32) {
        int d = i2 >> 5, j = i2 & 31;
        w2t[i2] = (h16)W2[j * DD + d];
    }
}

// ---------------------------------------------------------------------------
// Encoder via MFMA 16x16x32 f16 (round-6 core, verified) + fused fp8 mirror
// write. Runs AFTER countq/fillq (needs dinv; mir0 overlays the dead queue).
// x loads non-temporal (single-use stream).
// ---------------------------------------------------------------------------
__global__ __launch_bounds__(256)
void encoder_k(const float* __restrict__ x,
               const h16* __restrict__ w1t, const float* __restrict__ b1,
               const float* __restrict__ gamma, const float* __restrict__ beta,
               const h16* __restrict__ w2t, const float* __restrict__ b2,
               const float* __restrict__ dinv,
               float* __restrict__ h0, unsigned char* __restrict__ mir0, int N)
{
    __shared__ h16 hbuf[4][512];

    const int t = threadIdx.x;
    const int w = t >> 6, l = t & 63;
    const int c0 = l & 15, kg = l >> 4;
    const int gr0 = (blockIdx.x * 4 + w) * 16;
    int rowA = gr0 + c0; if (rowA >= N) rowA = N - 1;
    const float* xr = x + (size_t)rowA * F_IN;

    float b1a = b1[c0], b1b = b1[c0 + 16];
    f32x4 acc0 = {b1a, b1a, b1a, b1a};
    f32x4 acc1 = {b1b, b1b, b1b, b1b};

    const h16* w1a = w1t + c0 * 512 + kg * 8;
    const h16* w1b = w1a + 16 * 512;

    #pragma unroll 3
    for (int ks = 0; ks < 15; ++ks) {
        const int k0 = ks * 32;
        f32x4 xa = __builtin_nontemporal_load((const f32x4*)(xr + k0 + kg * 8));
        f32x4 xb = __builtin_nontemporal_load((const f32x4*)(xr + k0 + kg * 8 + 4));
        f16x8 af;
        af[0] = (h16)xa[0]; af[1] = (h16)xa[1]; af[2] = (h16)xa[2]; af[3] = (h16)xa[3];
        af[4] = (h16)xb[0]; af[5] = (h16)xb[1]; af[6] = (h16)xb[2]; af[7] = (h16)xb[3];
        f16x8 bf0 = *(const f16x8*)(w1a + k0);
        f16x8 bf1 = *(const f16x8*)(w1b + k0);
        acc0 = __builtin_amdgcn_mfma_f32_16x16x32_f16(af, bf0, acc0, 0, 0, 0);
        acc1 = __builtin_amdgcn_mfma_f32_16x16x32_f16(af, bf1, acc1, 0, 0, 0);
    }
    {
        f16x8 af;
        #pragma unroll
        for (int e = 0; e < 8; ++e) {
            int k = 480 + kg * 8 + e;
            af[e] = (k < F_IN) ? (h16)xr[k] : (h16)0.f;
        }
        f16x8 bf0 = *(const f16x8*)(w1a + 480);
        f16x8 bf1 = *(const f16x8*)(w1b + 480);
        acc0 = __builtin_amdgcn_mfma_f32_16x16x32_f16(af, bf0, acc0, 0, 0, 0);
        acc1 = __builtin_amdgcn_mfma_f32_16x16x32_f16(af, bf1, acc1, 0, 0, 0);
    }

    float g0 = gamma[c0], g1 = gamma[c0 + 16];
    float be0 = beta[c0], be1 = beta[c0 + 16];
    h16* hb = hbuf[w];
    #pragma unroll
    for (int i = 0; i < 4; ++i) {
        float a0 = acc0[i], a1 = acc1[i];
        float s = a0 + a1;
        s += __shfl_xor(s, 1); s += __shfl_xor(s, 2);
        s += __shfl_xor(s, 4); s += __shfl_xor(s, 8);
        float mu = s * (1.0f / 32.0f);
        float d0 = a0 - mu, d1 = a1 - mu;
        float vv = d0 * d0 + d1 * d1;
        vv += __shfl_xor(vv, 1); vv += __shfl_xor(vv, 2);
        vv += __shfl_xor(vv, 4); vv += __shfl_xor(vv, 8);
        float is = rsqrtf(vv * (1.0f / 32.0f) + LN_EPS);
        float h0v = fmaxf(fmaf(d0 * is, g0, be0), 0.f);
        float h1v = fmaxf(fmaf(d1 * is, g1, be1), 0.f);
        int r = kg * 4 + i;
        hb[r * 32 + ((((c0 >> 3) ^ i) & 3) << 3) + (c0 & 7)] = (h16)h0v;
        hb[r * 32 + ((((2 + (c0 >> 3)) ^ i) & 3) << 3) + (c0 & 7)] = (h16)h1v;
    }
    asm volatile("s_waitcnt lgkmcnt(0)" ::: "memory");
    __builtin_amdgcn_sched_barrier(0);

    f16x8 ah = *(const f16x8*)(hb + c0 * 32 + (((kg ^ (c0 & 3)) & 3) << 3));

    f32x4 oc[4];
    #pragma unroll
    for (int tl = 0; tl < 4; ++tl) {
        float bb = b2[tl * 16 + c0];
        f32x4 ci = {bb, bb, bb, bb};
        f16x8 bw = *(const f16x8*)(w2t + (tl * 16 + c0) * 32 + kg * 8);
        oc[tl] = __builtin_amdgcn_mfma_f32_16x16x32_f16(ah, bw, ci, 0, 0, 0);
    }

    #pragma unroll
    for (int i = 0; i < 4; ++i) {
        float ss = oc[0][i] * oc[0][i] + oc[1][i] * oc[1][i]
                 + oc[2][i] * oc[2][i] + oc[3][i] * oc[3][i];
        ss += __shfl_xor(ss, 1); ss += __shfl_xor(ss, 2);
        ss += __shfl_xor(ss, 4); ss += __shfl_xor(ss, 8);
        float sc = 1.0f / fmaxf(sqrtf(ss), 1e-12f);
        int row = gr0 + kg * 4 + i;
        if (row < N) {
            float dv = dinv[row];
            #pragma unroll
            for (int tl = 0; tl < 4; ++tl) {
                float val = oc[tl][i] * sc;
                h0[(size_t)row * DD + tl * 16 + c0] = val;
                mir0[(size_t)row * DD + tl * 16 + c0] = f2fp8(val * dv);
            }
        }
    }
}

// ---------------------------------------------------------------------------
__global__ void zero_k(int* __restrict__ p, int n)
{
    int i = blockIdx.x * blockDim.x + threadIdx.x;
    int stride = gridDim.x * blockDim.x;
    for (; i < n; i += stride) p[i] = 0;
}

// ---------------------------------------------------------------------------
// binq v2 (round-7/14, PROVEN on this input incl. the sorted self-loop tail):
// wave-autonomous two-pass span binner. Pass1 counts -> one aggregated
// atomic reserve; pass2 ballot-rank scatter. Handles arbitrary cohort skew.
// ---------------------------------------------------------------------------
__global__ __launch_bounds__(256)
void binq_k(const int* __restrict__ erow, const int* __restrict__ ecol, int M,
            unsigned* __restrict__ queue, int* __restrict__ qcnt,
            int cw, unsigned magic)
{
    const int wid  = blockIdx.x * 4 + (threadIdx.x >> 6);
    const int lane = threadIdx.x & 63;
    const int nw   = gridDim.x * 4;
    const int cls  = blockIdx.x & 7;

    for (int s0 = wid * SPAN; s0 < M; s0 += nw * SPAN) {
        const int e1 = min(s0 + SPAN, M);
        int tc[8] = {0, 0, 0, 0, 0, 0, 0, 0};
        for (int i = s0 + lane; i < e1; i += 64) {
            int c = __builtin_nontemporal_load(ecol + i);
            unsigned p = (unsigned)(((unsigned long long)(unsigned)c * magic) >> 32);
            #pragma unroll
            for (int pp = 0; pp < 8; ++pp) tc[pp] += (p == (unsigned)pp) ? 1 : 0;
        }
        #pragma unroll
        for (int pp = 0; pp < 8; ++pp) {
            #pragma unroll
            for (int m = 1; m < 64; m <<= 1) tc[pp] += __shfl_xor(tc[pp], m);
        }
        int val = tc[0];
        #pragma unroll
        for (int pp = 1; pp < 8; ++pp) val = (lane == pp) ? tc[pp] : val;
        int base = 0;
        if (lane < 8) base = atomicAdd(&qcnt[lane * 8 + cls], val);
        int bases[8], run[8];
        #pragma unroll
        for (int pp = 0; pp < 8; ++pp) { bases[pp] = __shfl(base, pp); run[pp] = 0; }

        for (int i0 = s0; i0 < e1; i0 += 64) {
            int i = i0 + lane;
            bool act = i < e1;
            int c = act ? ecol[i] : 0;
            int r = act ? erow[i] : 0;
            unsigned p = act ? (unsigned)(((unsigned long long)(unsigned)c * magic) >> 32)
                             : 0xFFu;
            unsigned pk = (unsigned)r | ((unsigned)(c - (int)p * cw) << 17);
            #pragma unroll
            for (int pp = 0; pp < 8; ++pp) {
                unsigned long long mm = __ballot(p == (unsigned)pp);
                if (p == (unsigned)pp) {
                    int rank = __popcll(mm & ((1ull << lane) - 1ull));
                    queue[(size_t)(pp * 8 + cls) * QCAP + bases[pp] + run[pp] + rank] = pk;
                }
                run[pp] += (int)__popcll(mm);
            }
        }
    }
}

// ---------------------------------------------------------------------------
// countq v5 (round-14, measured good): ONE block per cohort. LDS hist ->
// in-block exclusive scan -> deterministic qcnt-prefix base ->
// startv[N+1] (monotonic, sentinel M) + dinv. Zero global atomics.
// ---------------------------------------------------------------------------
__global__ __launch_bounds__(1024)
void countq_k(const unsigned* __restrict__ queue, const int* __restrict__ qcnt,
              int* __restrict__ startv, float* __restrict__ dinv, int cw, int N)
{
    __shared__ int lc[CW];
    __shared__ int ts[1024];
    __shared__ int qs[64];
    const int p = blockIdx.x;
    const int tid = threadIdx.x;

    for (int i = tid; i < cw; i += 1024) lc[i] = 0;
    if (tid < 64) qs[tid] = qcnt[tid];
    __syncthreads();

    #pragma unroll 1
    for (int sq = 0; sq < 8; ++sq) {
        const int n = qs[p * 8 + sq];
        const unsigned* q = queue + (size_t)(p * 8 + sq) * QCAP;
        int i = tid;
        for (; i + 3 * 1024 < n; i += 4 * 1024) {
            unsigned e0 = q[i];
            unsigned e1 = q[i + 1024];
            unsigned e2 = q[i + 2048];
            unsigned e3 = q[i + 3072];
            atomicAdd(&lc[e0 >> 17], 1);
            atomicAdd(&lc[e1 >> 17], 1);
            atomicAdd(&lc[e2 >> 17], 1);
            atomicAdd(&lc[e3 >> 17], 1);
        }
        for (; i < n; i += 1024)
            atomicAdd(&lc[q[i] >> 17], 1);
    }
    __syncthreads();

    for (int i = tid; i < cw; i += 1024) {
        int c = lc[i];
        dinv[p * cw + i] = (c > 0) ? rsqrtf((float)c) : 0.0f;
    }
    __syncthreads();

    const int CH = (cw + 1023) / 1024;
    const int lo = tid * CH;
    const int hi = min(lo + CH, cw);
    int sum = 0;
    for (int i = lo; i < hi; ++i) { int c = lc[i]; lc[i] = sum; sum += c; }
    ts[tid] = sum;
    __syncthreads();
    #pragma unroll
    for (int o = 1; o < 1024; o <<= 1) {
        int tmp = (tid >= o) ? ts[tid - o] : 0;
        __syncthreads();
        ts[tid] += tmp;
        __syncthreads();
    }
    const int chunkBase = (tid > 0) ? ts[tid - 1] : 0;

    int base = 0;
    for (int q = 0; q < p * 8; ++q) base += qs[q];

    for (int i = lo; i < hi; ++i)
        startv[p * cw + i] = base + chunkBase + lc[i];
    if (p == gridDim.x - 1 && tid == 1023) startv[N] = base + ts[1023]; // == M
}

// ---------------------------------------------------------------------------
// fillq v4 (round-14, measured good): LDS counting sort per window.
// ---------------------------------------------------------------------------
__global__ __launch_bounds__(1024)
void fillq_k(const unsigned* __restrict__ queue, const int* __restrict__ qcnt,
             const int* __restrict__ startv, int* __restrict__ cursor,
             int* __restrict__ csr_src, int cw)
{
    __shared__ int loff[FWN + 1];
    __shared__ int lcur[FWN];
    __shared__ unsigned lbuf[FCAP];

    const int tid = threadIdx.x;
    const int p  = blockIdx.x & 7;
    const int w  = blockIdx.x >> 3;
    const int c0 = w * FWN;
    const int wn = min(FWN, cw - c0);
    const int gn0 = p * cw + c0;

    for (int i = tid; i <= wn; i += 1024) loff[i] = startv[gn0 + i];
    for (int i = tid; i < wn; i += 1024) lcur[i] = 0;
    __syncthreads();

    const int base = loff[0];
    const int span = loff[wn] - base;

    if (span <= FCAP) {
        #pragma unroll 1
        for (int sq = 0; sq < 8; ++sq) {
            const int n = qcnt[p * 8 + sq];
            const unsigned* q = queue + (size_t)(p * 8 + sq) * QCAP;
            int i = tid;
            for (; i + 3 * 1024 < n; i += 4 * 1024) {
                unsigned e0 = q[i];
                unsigned e1 = q[i + 1024];
                unsigned e2 = q[i + 2048];
                unsigned e3 = q[i + 3072];
                int cl0 = (int)(e0 >> 17) - c0;
                int cl1 = (int)(e1 >> 17) - c0;
                int cl2 = (int)(e2 >> 17) - c0;
                int cl3 = (int)(e3 >> 17) - c0;
                if ((unsigned)cl0 < (unsigned)wn)
                    lbuf[loff[cl0] - base + atomicAdd(&lcur[cl0], 1)] = e0 & 0x1FFFFu;
                if ((unsigned)cl1 < (unsigned)wn)
                    lbuf[loff[cl1] - base + atomicAdd(&lcur[cl1], 1)] = e1 & 0x1FFFFu;
                if ((unsigned)cl2 < (unsigned)wn)
                    lbuf[loff[cl2] - base + atomicAdd(&lcur[cl2], 1)] = e2 & 0x1FFFFu;
                if ((unsigned)cl3 < (unsigned)wn)
                    lbuf[loff[cl3] - base + atomicAdd(&lcur[cl3], 1)] = e3 & 0x1FFFFu;
            }
            for (; i < n; i += 1024) {
                unsigned pk = q[i];
                int cl = (int)(pk >> 17) - c0;
                if ((unsigned)cl < (unsigned)wn)
                    lbuf[loff[cl] - base + atomicAdd(&lcur[cl], 1)] = pk & 0x1FFFFu;
            }
        }
        __syncthreads();
        for (int i = tid; i < span; i += 1024)
            csr_src[base + i] = (int)lbuf[i];
    } else {
        // pathological-degree fallback (never taken for random graphs)
        #pragma unroll 1
        for (int sq = 0; sq < 8; ++sq) {
            int n = qcnt[p * 8 + sq];
            const unsigned* q = queue + (size_t)(p * 8 + sq) * QCAP;
            for (int i = tid; i < n; i += 1024) {
                unsigned pk = q[i];
                int cl = (int)(pk >> 17) - c0;
                if ((unsigned)cl < (unsigned)wn) {
                    int c = gn0 + cl;
                    int pos = startv[c] + atomicAdd(&cursor[c], 1);
                    csr_src[pos] = (int)(pk & 0x1FFFFu);
                }
            }
        }
    }
}

// ---------------------------------------------------------------------------
// Propagation on fp8 mirror (round-14, measured good): 32 lanes/node,
// 8 independent gathers in flight, NT csr reads and h stores.
// hout[v] = dinv[v] * sum_r mirror[r]
// ---------------------------------------------------------------------------
__global__ __launch_bounds__(256)
void prop8_k(const unsigned char* __restrict__ min_, float* __restrict__ hout,
             unsigned short* __restrict__ mout,
             const int* __restrict__ startv,
             const int* __restrict__ csr_src, const float* __restrict__ dinv, int N)
{
    int v = blockIdx.x * 8 + (threadIdx.x >> 5);
    int l = threadIdx.x & 31;           // dim pair: dims 2l, 2l+1
    if (v >= N) return;
    int s = startv[v];
    int e = startv[v + 1];
    float dv = dinv[v];
    float a0 = 0.0f, a1 = 0.0f;
    int i = s;
    for (; i + 7 < e; i += 8) {
        int r0 = __builtin_nontemporal_load(csr_src + i + 0);
        int r1 = __builtin_nontemporal_load(csr_src + i + 1);
        int r2 = __builtin_nontemporal_load(csr_src + i + 2);
        int r3 = __builtin_nontemporal_load(csr_src + i + 3);
        int r4 = __builtin_nontemporal_load(csr_src + i + 4);
        int r5 = __builtin_nontemporal_load(csr_src + i + 5);
        int r6 = __builtin_nontemporal_load(csr_src + i + 6);
        int r7 = __builtin_nontemporal_load(csr_src + i + 7);
        unsigned short u0 = *(const unsigned short*)(min_ + (size_t)r0 * 64 + 2 * l);
        unsigned short u1 = *(const unsigned short*)(min_ + (size_t)r1 * 64 + 2 * l);
        unsigned short u2 = *(const unsigned short*)(min_ + (size_t)r2 * 64 + 2 * l);
        unsigned short u3 = *(const unsigned short*)(min_ + (size_t)r3 * 64 + 2 * l);
        unsigned short u4 = *(const unsigned short*)(min_ + (size_t)r4 * 64 + 2 * l);
        unsigned short u5 = *(const unsigned short*)(min_ + (size_t)r5 * 64 + 2 * l);
        unsigned short u6 = *(const unsigned short*)(min_ + (size_t)r6 * 64 + 2 * l);
        unsigned short u7 = *(const unsigned short*)(min_ + (size_t)r7 * 64 + 2 * l);
        a0 += fp82f((unsigned char)(u0 & 255)) + fp82f((unsigned char)(u1 & 255))
            + fp82f((unsigned char)(u2 & 255)) + fp82f((unsigned char)(u3 & 255))
            + fp82f((unsigned char)(u4 & 255)) + fp82f((unsigned char)(u5 & 255))
            + fp82f((unsigned char)(u6 & 255)) + fp82f((unsigned char)(u7 & 255));
        a1 += fp82f((unsigned char)(u0 >> 8)) + fp82f((unsigned char)(u1 >> 8))
            + fp82f((unsigned char)(u2 >> 8)) + fp82f((unsigned char)(u3 >> 8))
            + fp82f((unsigned char)(u4 >> 8)) + fp82f((unsigned char)(u5 >> 8))
            + fp82f((unsigned char)(u6 >> 8)) + fp82f((unsigned char)(u7 >> 8));
    }
    for (; i < e; ++i) {
        int r = __builtin_nontemporal_load(csr_src + i);
        unsigned short u = *(const unsigned short*)(min_ + (size_t)r * 64 + 2 * l);
        a0 += fp82f((unsigned char)(u & 255));
        a1 += fp82f((unsigned char)(u >> 8));
    }
    float r0 = dv * a0, r1 = dv * a1;
    f32x2 st = {r0, r1};
    __builtin_nontemporal_store(st, (f32x2*)(hout + (size_t)v * DD + 2 * l));
    if (mout) {
        unsigned short mv = (unsigned short)f2fp8(dv * r0)
                          | ((unsigned short)f2fp8(dv * r1) << 8);
        mout[(size_t)v * 32 + l] = mv;
    }
}

// ---------------------------------------------------------------------------
extern "C" void kernel_launch(void* const* d_in, const int* in_sizes, int n_in,
                              void* d_out, int out_size, void* d_ws, size_t ws_size,
                              hipStream_t stream)
{
    const float* x     = (const float*)d_in[0];
    const int*   ei    = (const int*)  d_in[1];
    const float* W1    = (const float*)d_in[2];
    const float* b1    = (const float*)d_in[3];
    const float* gamma = (const float*)d_in[4];
    const float* beta  = (const float*)d_in[5];
    const float* W2    = (const float*)d_in[6];
    const float* b2    = (const float*)d_in[7];
    float* out = (float*)d_out;

    const int N = in_sizes[0] / F_IN;       // 100000
    const int M = in_sizes[1] / 2;          // 3300000
    const int cw = (N + 7) / 8;             // 12500
    const unsigned magic = (unsigned)((0x100000000ULL + cw - 1) / cw);
    const int* erow = ei;
    const int* ecol = ei + M;

    // workspace layout (ints)
    int* wsI = (int*)d_ws;
    int*   cursor  = wsI;                               // N (fillq fallback)
    int*   qcnt    = wsI + N;                           // 64 (+4 pad)
    int*   startv  = wsI + N + 68;                      // N+1
    float* dinv    = (float*)(wsI + 2 * N + 70);        // N
    h16*   w1t     = (h16*)(wsI + 3 * N + 70);          // 8192 ints
    h16*   w2t     = (h16*)(wsI + 3 * N + 70 + 8192);   // 1024 ints
    int*   csr_src = wsI + 3 * N + 70 + 9216;           // M
    unsigned* queue = (unsigned*)(csr_src + M);         // 64*QCAP u32 (25.6MB)
    unsigned char* mir0 = (unsigned char*)queue;        // overlays queue (dead after fillq)
    unsigned char* mir1 = mir0 + (size_t)N * 64;        // 6.4MB each

    // zero cursor + qcnt
    zero_k<<<512, 256, 0, stream>>>(wsI, N + 68);
    prep_k<<<(32 * 512 + 64 * 32 + 255) / 256, 256, 0, stream>>>(W1, W2, w1t, w2t);

    binq_k<<<256, 256, 0, stream>>>(erow, ecol, M, queue, qcnt, cw, magic);

    countq_k<<<8, 1024, 0, stream>>>(queue, qcnt, startv, dinv, cw, N);

    const int NWF = (cw + FWN - 1) / FWN;   // 28
    fillq_k<<<NWF * 8, 1024, 0, stream>>>(queue, qcnt, startv, cursor, csr_src, cw);

    float* h0 = out;
    float* h1 = out + (size_t)N * DD;
    float* h2 = out + 2 * (size_t)N * DD;

    // encoder after fillq: writes h0 + fp8 mir0 (queue region is dead now)
    encoder_k<<<(N + 63) / 64, 256, 0, stream>>>(x, w1t, b1, gamma, beta, w2t, b2,
                                                 dinv, h0, mir0, N);

    prop8_k<<<(N + 7) / 8, 256, 0, stream>>>(mir0, h1, (unsigned short*)mir1,
                                             startv, csr_src, dinv, N);
    prop8_k<<<(N + 7) / 8, 256, 0, stream>>>(mir1, h2, (unsigned short*)nullptr,
                                             startv, csr_src, dinv, N);
}

// Round 17
// 440.859 us; speedup vs baseline: 1.0243x; 1.0243x over previous
//
#include <hip/hip_runtime.h>
#include <hip/hip_fp8.h>

#define F_IN 500
#define HH 32
#define DD 64
#define LN_EPS 1e-6f
#define QCAP 100000     // slots per (cohort, writer-class) queue
#define SPAN 4096       // edges per wave in binq
#define FWN 448         // fillq window (nodes)
#define FCAP 16384      // fillq LDS entry capacity (64 KB)
#define CW 12500        // cohort width (N/8)

typedef float f32x4 __attribute__((ext_vector_type(4)));
typedef float f32x2 __attribute__((ext_vector_type(2)));
typedef _Float16 f16x8 __attribute__((ext_vector_type(8)));
typedef _Float16 h16;

__device__ __forceinline__ unsigned char f2fp8(float x) {
    __hip_fp8_e4m3 t(x);
    return (unsigned char)t.__x;
}
__device__ __forceinline__ float fp82f(unsigned char b) {
    __hip_fp8_e4m3 t;
    t.__x = (__hip_fp8_storage_t)b;
    return (float)t;
}

// ---------------------------------------------------------------------------
// prep: W1T f16 [32 j][512 k] (zero-padded k>=500), W2T f16 [64 d][32 j]
// ---------------------------------------------------------------------------
__global__ __launch_bounds__(256)
void prep_k(const float* __restrict__ W1, const float* __restrict__ W2,
            h16* __restrict__ w1t, h16* __restrict__ w2t)
{
    int i = blockIdx.x * 256 + threadIdx.x;
    if (i < 32 * 512) {
        int j = i >> 9, k = i & 511;
        w1t[i] = (k < F_IN) ? (h16)W1[k * HH + j] : (h16)0.f;
    }
    int i2 = i - 32 * 512;
    if (i2 >= 0 && i2 < 64 * 32) {
        int d = i2 >> 5, j = i2 & 31;
        w2t[i2] = (h16)W2[j * DD + d];
    }
}

// ---------------------------------------------------------------------------
// Encoder via MFMA 16x16x32 f16 (round-6 core, verified) + fused fp8 mirror
// write. Runs AFTER countq/fillq (needs dinv; mir0 overlays the dead queue).
// x loads non-temporal (genuinely single-use stream).
// ---------------------------------------------------------------------------
__global__ __launch_bounds__(256)
void encoder_k(const float* __restrict__ x,
               const h16* __restrict__ w1t, const float* __restrict__ b1,
               const float* __restrict__ gamma, const float* __restrict__ beta,
               const h16* __restrict__ w2t, const float* __restrict__ b2,
               const float* __restrict__ dinv,
               float* __restrict__ h0, unsigned char* __restrict__ mir0, int N)
{
    __shared__ h16 hbuf[4][512];

    const int t = threadIdx.x;
    const int w = t >> 6, l = t & 63;
    const int c0 = l & 15, kg = l >> 4;
    const int gr0 = (blockIdx.x * 4 + w) * 16;
    int rowA = gr0 + c0; if (rowA >= N) rowA = N - 1;
    const float* xr = x + (size_t)rowA * F_IN;

    float b1a = b1[c0], b1b = b1[c0 + 16];
    f32x4 acc0 = {b1a, b1a, b1a, b1a};
    f32x4 acc1 = {b1b, b1b, b1b, b1b};

    const h16* w1a = w1t + c0 * 512 + kg * 8;
    const h16* w1b = w1a + 16 * 512;

    #pragma unroll 3
    for (int ks = 0; ks < 15; ++ks) {
        const int k0 = ks * 32;
        f32x4 xa = __builtin_nontemporal_load((const f32x4*)(xr + k0 + kg * 8));
        f32x4 xb = __builtin_nontemporal_load((const f32x4*)(xr + k0 + kg * 8 + 4));
        f16x8 af;
        af[0] = (h16)xa[0]; af[1] = (h16)xa[1]; af[2] = (h16)xa[2]; af[3] = (h16)xa[3];
        af[4] = (h16)xb[0]; af[5] = (h16)xb[1]; af[6] = (h16)xb[2]; af[7] = (h16)xb[3];
        f16x8 bf0 = *(const f16x8*)(w1a + k0);
        f16x8 bf1 = *(const f16x8*)(w1b + k0);
        acc0 = __builtin_amdgcn_mfma_f32_16x16x32_f16(af, bf0, acc0, 0, 0, 0);
        acc1 = __builtin_amdgcn_mfma_f32_16x16x32_f16(af, bf1, acc1, 0, 0, 0);
    }
    {
        f16x8 af;
        #pragma unroll
        for (int e = 0; e < 8; ++e) {
            int k = 480 + kg * 8 + e;
            af[e] = (k < F_IN) ? (h16)xr[k] : (h16)0.f;
        }
        f16x8 bf0 = *(const f16x8*)(w1a + 480);
        f16x8 bf1 = *(const f16x8*)(w1b + 480);
        acc0 = __builtin_amdgcn_mfma_f32_16x16x32_f16(af, bf0, acc0, 0, 0, 0);
        acc1 = __builtin_amdgcn_mfma_f32_16x16x32_f16(af, bf1, acc1, 0, 0, 0);
    }

    float g0 = gamma[c0], g1 = gamma[c0 + 16];
    float be0 = beta[c0], be1 = beta[c0 + 16];
    h16* hb = hbuf[w];
    #pragma unroll
    for (int i = 0; i < 4; ++i) {
        float a0 = acc0[i], a1 = acc1[i];
        float s = a0 + a1;
        s += __shfl_xor(s, 1); s += __shfl_xor(s, 2);
        s += __shfl_xor(s, 4); s += __shfl_xor(s, 8);
        float mu = s * (1.0f / 32.0f);
        float d0 = a0 - mu, d1 = a1 - mu;
        float vv = d0 * d0 + d1 * d1;
        vv += __shfl_xor(vv, 1); vv += __shfl_xor(vv, 2);
        vv += __shfl_xor(vv, 4); vv += __shfl_xor(vv, 8);
        float is = rsqrtf(vv * (1.0f / 32.0f) + LN_EPS);
        float h0v = fmaxf(fmaf(d0 * is, g0, be0), 0.f);
        float h1v = fmaxf(fmaf(d1 * is, g1, be1), 0.f);
        int r = kg * 4 + i;
        hb[r * 32 + ((((c0 >> 3) ^ i) & 3) << 3) + (c0 & 7)] = (h16)h0v;
        hb[r * 32 + ((((2 + (c0 >> 3)) ^ i) & 3) << 3) + (c0 & 7)] = (h16)h1v;
    }
    asm volatile("s_waitcnt lgkmcnt(0)" ::: "memory");
    __builtin_amdgcn_sched_barrier(0);

    f16x8 ah = *(const f16x8*)(hb + c0 * 32 + (((kg ^ (c0 & 3)) & 3) << 3));

    f32x4 oc[4];
    #pragma unroll
    for (int tl = 0; tl < 4; ++tl) {
        float bb = b2[tl * 16 + c0];
        f32x4 ci = {bb, bb, bb, bb};
        f16x8 bw = *(const f16x8*)(w2t + (tl * 16 + c0) * 32 + kg * 8);
        oc[tl] = __builtin_amdgcn_mfma_f32_16x16x32_f16(ah, bw, ci, 0, 0, 0);
    }

    #pragma unroll
    for (int i = 0; i < 4; ++i) {
        float ss = oc[0][i] * oc[0][i] + oc[1][i] * oc[1][i]
                 + oc[2][i] * oc[2][i] + oc[3][i] * oc[3][i];
        ss += __shfl_xor(ss, 1); ss += __shfl_xor(ss, 2);
        ss += __shfl_xor(ss, 4); ss += __shfl_xor(ss, 8);
        float sc = 1.0f / fmaxf(sqrtf(ss), 1e-12f);
        int row = gr0 + kg * 4 + i;
        if (row < N) {
            float dv = dinv[row];
            #pragma unroll
            for (int tl = 0; tl < 4; ++tl) {
                float val = oc[tl][i] * sc;
                h0[(size_t)row * DD + tl * 16 + c0] = val;
                mir0[(size_t)row * DD + tl * 16 + c0] = f2fp8(val * dv);
            }
        }
    }
}

// ---------------------------------------------------------------------------
__global__ void zero_k(int* __restrict__ p, int n)
{
    int i = blockIdx.x * blockDim.x + threadIdx.x;
    int stride = gridDim.x * blockDim.x;
    for (; i < n; i += stride) p[i] = 0;
}

// ---------------------------------------------------------------------------
// binq v2 (round-7/14, PROVEN): wave-autonomous two-pass span binner.
// Pass-1 ecol load is a NORMAL load — it deliberately warms L1/L2 for
// pass 2's re-read (round-16's NT hint here cost +35 µs).
// ---------------------------------------------------------------------------
__global__ __launch_bounds__(256)
void binq_k(const int* __restrict__ erow, const int* __restrict__ ecol, int M,
            unsigned* __restrict__ queue, int* __restrict__ qcnt,
            int cw, unsigned magic)
{
    const int wid  = blockIdx.x * 4 + (threadIdx.x >> 6);
    const int lane = threadIdx.x & 63;
    const int nw   = gridDim.x * 4;
    const int cls  = blockIdx.x & 7;

    for (int s0 = wid * SPAN; s0 < M; s0 += nw * SPAN) {
        const int e1 = min(s0 + SPAN, M);
        int tc[8] = {0, 0, 0, 0, 0, 0, 0, 0};
        for (int i = s0 + lane; i < e1; i += 64) {
            int c = ecol[i];                     // cache-filling (prefetch for pass 2)
            unsigned p = (unsigned)(((unsigned long long)(unsigned)c * magic) >> 32);
            #pragma unroll
            for (int pp = 0; pp < 8; ++pp) tc[pp] += (p == (unsigned)pp) ? 1 : 0;
        }
        #pragma unroll
        for (int pp = 0; pp < 8; ++pp) {
            #pragma unroll
            for (int m = 1; m < 64; m <<= 1) tc[pp] += __shfl_xor(tc[pp], m);
        }
        int val = tc[0];
        #pragma unroll
        for (int pp = 1; pp < 8; ++pp) val = (lane == pp) ? tc[pp] : val;
        int base = 0;
        if (lane < 8) base = atomicAdd(&qcnt[lane * 8 + cls], val);
        int bases[8], run[8];
        #pragma unroll
        for (int pp = 0; pp < 8; ++pp) { bases[pp] = __shfl(base, pp); run[pp] = 0; }

        for (int i0 = s0; i0 < e1; i0 += 64) {
            int i = i0 + lane;
            bool act = i < e1;
            int c = act ? ecol[i] : 0;
            int r = act ? erow[i] : 0;
            unsigned p = act ? (unsigned)(((unsigned long long)(unsigned)c * magic) >> 32)
                             : 0xFFu;
            unsigned pk = (unsigned)r | ((unsigned)(c - (int)p * cw) << 17);
            #pragma unroll
            for (int pp = 0; pp < 8; ++pp) {
                unsigned long long mm = __ballot(p == (unsigned)pp);
                if (p == (unsigned)pp) {
                    int rank = __popcll(mm & ((1ull << lane) - 1ull));
                    queue[(size_t)(pp * 8 + cls) * QCAP + bases[pp] + run[pp] + rank] = pk;
                }
                run[pp] += (int)__popcll(mm);
            }
        }
    }
}

// ---------------------------------------------------------------------------
// countq v5 (round-14, measured good): ONE block per cohort. LDS hist ->
// in-block exclusive scan -> deterministic qcnt-prefix base ->
// startv[N+1] (monotonic, sentinel M) + dinv. Zero global atomics.
// ---------------------------------------------------------------------------
__global__ __launch_bounds__(1024)
void countq_k(const unsigned* __restrict__ queue, const int* __restrict__ qcnt,
              int* __restrict__ startv, float* __restrict__ dinv, int cw, int N)
{
    __shared__ int lc[CW];
    __shared__ int ts[1024];
    __shared__ int qs[64];
    const int p = blockIdx.x;
    const int tid = threadIdx.x;

    for (int i = tid; i < cw; i += 1024) lc[i] = 0;
    if (tid < 64) qs[tid] = qcnt[tid];
    __syncthreads();

    #pragma unroll 1
    for (int sq = 0; sq < 8; ++sq) {
        const int n = qs[p * 8 + sq];
        const unsigned* q = queue + (size_t)(p * 8 + sq) * QCAP;
        int i = tid;
        for (; i + 3 * 1024 < n; i += 4 * 1024) {
            unsigned e0 = q[i];
            unsigned e1 = q[i + 1024];
            unsigned e2 = q[i + 2048];
            unsigned e3 = q[i + 3072];
            atomicAdd(&lc[e0 >> 17], 1);
            atomicAdd(&lc[e1 >> 17], 1);
            atomicAdd(&lc[e2 >> 17], 1);
            atomicAdd(&lc[e3 >> 17], 1);
        }
        for (; i < n; i += 1024)
            atomicAdd(&lc[q[i] >> 17], 1);
    }
    __syncthreads();

    for (int i = tid; i < cw; i += 1024) {
        int c = lc[i];
        dinv[p * cw + i] = (c > 0) ? rsqrtf((float)c) : 0.0f;
    }
    __syncthreads();

    const int CH = (cw + 1023) / 1024;
    const int lo = tid * CH;
    const int hi = min(lo + CH, cw);
    int sum = 0;
    for (int i = lo; i < hi; ++i) { int c = lc[i]; lc[i] = sum; sum += c; }
    ts[tid] = sum;
    __syncthreads();
    #pragma unroll
    for (int o = 1; o < 1024; o <<= 1) {
        int tmp = (tid >= o) ? ts[tid - o] : 0;
        __syncthreads();
        ts[tid] += tmp;
        __syncthreads();
    }
    const int chunkBase = (tid > 0) ? ts[tid - 1] : 0;

    int base = 0;
    for (int q = 0; q < p * 8; ++q) base += qs[q];

    for (int i = lo; i < hi; ++i)
        startv[p * cw + i] = base + chunkBase + lc[i];
    if (p == gridDim.x - 1 && tid == 1023) startv[N] = base + ts[1023]; // == M
}

// ---------------------------------------------------------------------------
// fillq v4 (round-14, measured good): LDS counting sort per window.
// ---------------------------------------------------------------------------
__global__ __launch_bounds__(1024)
void fillq_k(const unsigned* __restrict__ queue, const int* __restrict__ qcnt,
             const int* __restrict__ startv, int* __restrict__ cursor,
             int* __restrict__ csr_src, int cw)
{
    __shared__ int loff[FWN + 1];
    __shared__ int lcur[FWN];
    __shared__ unsigned lbuf[FCAP];

    const int tid = threadIdx.x;
    const int p  = blockIdx.x & 7;
    const int w  = blockIdx.x >> 3;
    const int c0 = w * FWN;
    const int wn = min(FWN, cw - c0);
    const int gn0 = p * cw + c0;

    for (int i = tid; i <= wn; i += 1024) loff[i] = startv[gn0 + i];
    for (int i = tid; i < wn; i += 1024) lcur[i] = 0;
    __syncthreads();

    const int base = loff[0];
    const int span = loff[wn] - base;

    if (span <= FCAP) {
        #pragma unroll 1
        for (int sq = 0; sq < 8; ++sq) {
            const int n = qcnt[p * 8 + sq];
            const unsigned* q = queue + (size_t)(p * 8 + sq) * QCAP;
            int i = tid;
            for (; i + 3 * 1024 < n; i += 4 * 1024) {
                unsigned e0 = q[i];
                unsigned e1 = q[i + 1024];
                unsigned e2 = q[i + 2048];
                unsigned e3 = q[i + 3072];
                int cl0 = (int)(e0 >> 17) - c0;
                int cl1 = (int)(e1 >> 17) - c0;
                int cl2 = (int)(e2 >> 17) - c0;
                int cl3 = (int)(e3 >> 17) - c0;
                if ((unsigned)cl0 < (unsigned)wn)
                    lbuf[loff[cl0] - base + atomicAdd(&lcur[cl0], 1)] = e0 & 0x1FFFFu;
                if ((unsigned)cl1 < (unsigned)wn)
                    lbuf[loff[cl1] - base + atomicAdd(&lcur[cl1], 1)] = e1 & 0x1FFFFu;
                if ((unsigned)cl2 < (unsigned)wn)
                    lbuf[loff[cl2] - base + atomicAdd(&lcur[cl2], 1)] = e2 & 0x1FFFFu;
                if ((unsigned)cl3 < (unsigned)wn)
                    lbuf[loff[cl3] - base + atomicAdd(&lcur[cl3], 1)] = e3 & 0x1FFFFu;
            }
            for (; i < n; i += 1024) {
                unsigned pk = q[i];
                int cl = (int)(pk >> 17) - c0;
                if ((unsigned)cl < (unsigned)wn)
                    lbuf[loff[cl] - base + atomicAdd(&lcur[cl], 1)] = pk & 0x1FFFFu;
            }
        }
        __syncthreads();
        for (int i = tid; i < span; i += 1024)
            csr_src[base + i] = (int)lbuf[i];
    } else {
        // pathological-degree fallback (never taken for random graphs)
        #pragma unroll 1
        for (int sq = 0; sq < 8; ++sq) {
            int n = qcnt[p * 8 + sq];
            const unsigned* q = queue + (size_t)(p * 8 + sq) * QCAP;
            for (int i = tid; i < n; i += 1024) {
                unsigned pk = q[i];
                int cl = (int)(pk >> 17) - c0;
                if ((unsigned)cl < (unsigned)wn) {
                    int c = gn0 + cl;
                    int pos = startv[c] + atomicAdd(&cursor[c], 1);
                    csr_src[pos] = (int)(pk & 0x1FFFFu);
                }
            }
        }
    }
}

// ---------------------------------------------------------------------------
// Propagation on fp8 mirror (round-14, measured good): 32 lanes/node,
// 8 independent gathers in flight, NT csr reads and h stores.
// hout[v] = dinv[v] * sum_r mirror[r]
// ---------------------------------------------------------------------------
__global__ __launch_bounds__(256)
void prop8_k(const unsigned char* __restrict__ min_, float* __restrict__ hout,
             unsigned short* __restrict__ mout,
             const int* __restrict__ startv,
             const int* __restrict__ csr_src, const float* __restrict__ dinv, int N)
{
    int v = blockIdx.x * 8 + (threadIdx.x >> 5);
    int l = threadIdx.x & 31;           // dim pair: dims 2l, 2l+1
    if (v >= N) return;
    int s = startv[v];
    int e = startv[v + 1];
    float dv = dinv[v];
    float a0 = 0.0f, a1 = 0.0f;
    int i = s;
    for (; i + 7 < e; i += 8) {
        int r0 = __builtin_nontemporal_load(csr_src + i + 0);
        int r1 = __builtin_nontemporal_load(csr_src + i + 1);
        int r2 = __builtin_nontemporal_load(csr_src + i + 2);
        int r3 = __builtin_nontemporal_load(csr_src + i + 3);
        int r4 = __builtin_nontemporal_load(csr_src + i + 4);
        int r5 = __builtin_nontemporal_load(csr_src + i + 5);
        int r6 = __builtin_nontemporal_load(csr_src + i + 6);
        int r7 = __builtin_nontemporal_load(csr_src + i + 7);
        unsigned short u0 = *(const unsigned short*)(min_ + (size_t)r0 * 64 + 2 * l);
        unsigned short u1 = *(const unsigned short*)(min_ + (size_t)r1 * 64 + 2 * l);
        unsigned short u2 = *(const unsigned short*)(min_ + (size_t)r2 * 64 + 2 * l);
        unsigned short u3 = *(const unsigned short*)(min_ + (size_t)r3 * 64 + 2 * l);
        unsigned short u4 = *(const unsigned short*)(min_ + (size_t)r4 * 64 + 2 * l);
        unsigned short u5 = *(const unsigned short*)(min_ + (size_t)r5 * 64 + 2 * l);
        unsigned short u6 = *(const unsigned short*)(min_ + (size_t)r6 * 64 + 2 * l);
        unsigned short u7 = *(const unsigned short*)(min_ + (size_t)r7 * 64 + 2 * l);
        a0 += fp82f((unsigned char)(u0 & 255)) + fp82f((unsigned char)(u1 & 255))
            + fp82f((unsigned char)(u2 & 255)) + fp82f((unsigned char)(u3 & 255))
            + fp82f((unsigned char)(u4 & 255)) + fp82f((unsigned char)(u5 & 255))
            + fp82f((unsigned char)(u6 & 255)) + fp82f((unsigned char)(u7 & 255));
        a1 += fp82f((unsigned char)(u0 >> 8)) + fp82f((unsigned char)(u1 >> 8))
            + fp82f((unsigned char)(u2 >> 8)) + fp82f((unsigned char)(u3 >> 8))
            + fp82f((unsigned char)(u4 >> 8)) + fp82f((unsigned char)(u5 >> 8))
            + fp82f((unsigned char)(u6 >> 8)) + fp82f((unsigned char)(u7 >> 8));
    }
    for (; i < e; ++i) {
        int r = __builtin_nontemporal_load(csr_src + i);
        unsigned short u = *(const unsigned short*)(min_ + (size_t)r * 64 + 2 * l);
        a0 += fp82f((unsigned char)(u & 255));
        a1 += fp82f((unsigned char)(u >> 8));
    }
    float r0 = dv * a0, r1 = dv * a1;
    f32x2 st = {r0, r1};
    __builtin_nontemporal_store(st, (f32x2*)(hout + (size_t)v * DD + 2 * l));
    if (mout) {
        unsigned short mv = (unsigned short)f2fp8(dv * r0)
                          | ((unsigned short)f2fp8(dv * r1) << 8);
        mout[(size_t)v * 32 + l] = mv;
    }
}

// ---------------------------------------------------------------------------
extern "C" void kernel_launch(void* const* d_in, const int* in_sizes, int n_in,
                              void* d_out, int out_size, void* d_ws, size_t ws_size,
                              hipStream_t stream)
{
    const float* x     = (const float*)d_in[0];
    const int*   ei    = (const int*)  d_in[1];
    const float* W1    = (const float*)d_in[2];
    const float* b1    = (const float*)d_in[3];
    const float* gamma = (const float*)d_in[4];
    const float* beta  = (const float*)d_in[5];
    const float* W2    = (const float*)d_in[6];
    const float* b2    = (const float*)d_in[7];
    float* out = (float*)d_out;

    const int N = in_sizes[0] / F_IN;       // 100000
    const int M = in_sizes[1] / 2;          // 3300000
    const int cw = (N + 7) / 8;             // 12500
    const unsigned magic = (unsigned)((0x100000000ULL + cw - 1) / cw);
    const int* erow = ei;
    const int* ecol = ei + M;

    // workspace layout (ints)
    int* wsI = (int*)d_ws;
    int*   cursor  = wsI;                               // N (fillq fallback)
    int*   qcnt    = wsI + N;                           // 64 (+4 pad)
    int*   startv  = wsI + N + 68;                      // N+1
    float* dinv    = (float*)(wsI + 2 * N + 70);        // N
    h16*   w1t     = (h16*)(wsI + 3 * N + 70);          // 8192 ints
    h16*   w2t     = (h16*)(wsI + 3 * N + 70 + 8192);   // 1024 ints
    int*   csr_src = wsI + 3 * N + 70 + 9216;           // M
    unsigned* queue = (unsigned*)(csr_src + M);         // 64*QCAP u32 (25.6MB)
    unsigned char* mir0 = (unsigned char*)queue;        // overlays queue (dead after fillq)
    unsigned char* mir1 = mir0 + (size_t)N * 64;        // 6.4MB each

    // zero cursor + qcnt
    zero_k<<<512, 256, 0, stream>>>(wsI, N + 68);
    prep_k<<<(32 * 512 + 64 * 32 + 255) / 256, 256, 0, stream>>>(W1, W2, w1t, w2t);

    binq_k<<<256, 256, 0, stream>>>(erow, ecol, M, queue, qcnt, cw, magic);

    countq_k<<<8, 1024, 0, stream>>>(queue, qcnt, startv, dinv, cw, N);

    const int NWF = (cw + FWN - 1) / FWN;   // 28
    fillq_k<<<NWF * 8, 1024, 0, stream>>>(queue, qcnt, startv, cursor, csr_src, cw);

    float* h0 = out;
    float* h1 = out + (size_t)N * DD;
    float* h2 = out + 2 * (size_t)N * DD;

    // encoder after fillq: writes h0 + fp8 mir0 (queue region is dead now)
    encoder_k<<<(N + 63) / 64, 256, 0, stream>>>(x, w1t, b1, gamma, beta, w2t, b2,
                                                 dinv, h0, mir0, N);

    prop8_k<<<(N + 7) / 8, 256, 0, stream>>>(mir0, h1, (unsigned short*)mir1,
                                             startv, csr_src, dinv, N);
    prop8_k<<<(N + 7) / 8, 256, 0, stream>>>(mir1, h2, (unsigned short*)nullptr,
                                             startv, csr_src, dinv, N);
}

// Round 18
// 415.833 us; speedup vs baseline: 1.0859x; 1.0602x over previous
//
#include <hip/hip_runtime.h>
#include <hip/hip_fp8.h>

#define F_IN 500
#define HH 32
#define DD 64
#define LN_EPS 1e-6f
#define QCAP 100000     // slots per (cohort, writer-class) queue
#define SPAN 4096       // edges per wave in binq
#define FWN 448         // fillq window (nodes)
#define FCAP 16384      // fillq LDS entry capacity (64 KB)
#define CW 12500        // cohort width (N/8)

typedef float f32x4 __attribute__((ext_vector_type(4)));
typedef float f32x2 __attribute__((ext_vector_type(2)));
typedef _Float16 f16x8 __attribute__((ext_vector_type(8)));
typedef _Float16 h16;

__device__ __forceinline__ unsigned char f2fp8(float x) {
    __hip_fp8_e4m3 t(x);
    return (unsigned char)t.__x;
}
__device__ __forceinline__ float fp82f(unsigned char b) {
    __hip_fp8_e4m3 t;
    t.__x = (__hip_fp8_storage_t)b;
    return (float)t;
}

// ---------------------------------------------------------------------------
// prep: W1T f16 [32 j][512 k] (zero-padded k>=500), W2T f16 [64 d][32 j]
// ---------------------------------------------------------------------------
__global__ __launch_bounds__(256)
void prep_k(const float* __restrict__ W1, const float* __restrict__ W2,
            h16* __restrict__ w1t, h16* __restrict__ w2t)
{
    int i = blockIdx.x * 256 + threadIdx.x;
    if (i < 32 * 512) {
        int j = i >> 9, k = i & 511;
        w1t[i] = (k < F_IN) ? (h16)W1[k * HH + j] : (h16)0.f;
    }
    int i2 = i - 32 * 512;
    if (i2 >= 0 && i2 < 64 * 32) {
        int d = i2 >> 5, j = i2 & 31;
        w2t[i2] = (h16)W2[j * DD + d];
    }
}

// ---------------------------------------------------------------------------
// Encoder via MFMA 16x16x32 f16 (round-6, verified absmax; round-14 position).
// ---------------------------------------------------------------------------
__global__ __launch_bounds__(256)
void encoder_k(const float* __restrict__ x,
               const h16* __restrict__ w1t, const float* __restrict__ b1,
               const float* __restrict__ gamma, const float* __restrict__ beta,
               const h16* __restrict__ w2t, const float* __restrict__ b2,
               float* __restrict__ h0, int N)
{
    __shared__ h16 hbuf[4][512];

    const int t = threadIdx.x;
    const int w = t >> 6, l = t & 63;
    const int c0 = l & 15, kg = l >> 4;
    const int gr0 = (blockIdx.x * 4 + w) * 16;
    int rowA = gr0 + c0; if (rowA >= N) rowA = N - 1;
    const float* xr = x + (size_t)rowA * F_IN;

    float b1a = b1[c0], b1b = b1[c0 + 16];
    f32x4 acc0 = {b1a, b1a, b1a, b1a};
    f32x4 acc1 = {b1b, b1b, b1b, b1b};

    const h16* w1a = w1t + c0 * 512 + kg * 8;
    const h16* w1b = w1a + 16 * 512;

    #pragma unroll 3
    for (int ks = 0; ks < 15; ++ks) {
        const int k0 = ks * 32;
        f32x4 xa = *(const f32x4*)(xr + k0 + kg * 8);
        f32x4 xb = *(const f32x4*)(xr + k0 + kg * 8 + 4);
        f16x8 af;
        af[0] = (h16)xa[0]; af[1] = (h16)xa[1]; af[2] = (h16)xa[2]; af[3] = (h16)xa[3];
        af[4] = (h16)xb[0]; af[5] = (h16)xb[1]; af[6] = (h16)xb[2]; af[7] = (h16)xb[3];
        f16x8 bf0 = *(const f16x8*)(w1a + k0);
        f16x8 bf1 = *(const f16x8*)(w1b + k0);
        acc0 = __builtin_amdgcn_mfma_f32_16x16x32_f16(af, bf0, acc0, 0, 0, 0);
        acc1 = __builtin_amdgcn_mfma_f32_16x16x32_f16(af, bf1, acc1, 0, 0, 0);
    }
    {
        f16x8 af;
        #pragma unroll
        for (int e = 0; e < 8; ++e) {
            int k = 480 + kg * 8 + e;
            af[e] = (k < F_IN) ? (h16)xr[k] : (h16)0.f;
        }
        f16x8 bf0 = *(const f16x8*)(w1a + 480);
        f16x8 bf1 = *(const f16x8*)(w1b + 480);
        acc0 = __builtin_amdgcn_mfma_f32_16x16x32_f16(af, bf0, acc0, 0, 0, 0);
        acc1 = __builtin_amdgcn_mfma_f32_16x16x32_f16(af, bf1, acc1, 0, 0, 0);
    }

    float g0 = gamma[c0], g1 = gamma[c0 + 16];
    float be0 = beta[c0], be1 = beta[c0 + 16];
    h16* hb = hbuf[w];
    #pragma unroll
    for (int i = 0; i < 4; ++i) {
        float a0 = acc0[i], a1 = acc1[i];
        float s = a0 + a1;
        s += __shfl_xor(s, 1); s += __shfl_xor(s, 2);
        s += __shfl_xor(s, 4); s += __shfl_xor(s, 8);
        float mu = s * (1.0f / 32.0f);
        float d0 = a0 - mu, d1 = a1 - mu;
        float vv = d0 * d0 + d1 * d1;
        vv += __shfl_xor(vv, 1); vv += __shfl_xor(vv, 2);
        vv += __shfl_xor(vv, 4); vv += __shfl_xor(vv, 8);
        float is = rsqrtf(vv * (1.0f / 32.0f) + LN_EPS);
        float h0v = fmaxf(fmaf(d0 * is, g0, be0), 0.f);
        float h1v = fmaxf(fmaf(d1 * is, g1, be1), 0.f);
        int r = kg * 4 + i;
        hb[r * 32 + ((((c0 >> 3) ^ i) & 3) << 3) + (c0 & 7)] = (h16)h0v;
        hb[r * 32 + ((((2 + (c0 >> 3)) ^ i) & 3) << 3) + (c0 & 7)] = (h16)h1v;
    }
    asm volatile("s_waitcnt lgkmcnt(0)" ::: "memory");
    __builtin_amdgcn_sched_barrier(0);

    f16x8 ah = *(const f16x8*)(hb + c0 * 32 + (((kg ^ (c0 & 3)) & 3) << 3));

    f32x4 oc[4];
    #pragma unroll
    for (int tl = 0; tl < 4; ++tl) {
        float bb = b2[tl * 16 + c0];
        f32x4 ci = {bb, bb, bb, bb};
        f16x8 bw = *(const f16x8*)(w2t + (tl * 16 + c0) * 32 + kg * 8);
        oc[tl] = __builtin_amdgcn_mfma_f32_16x16x32_f16(ah, bw, ci, 0, 0, 0);
    }

    #pragma unroll
    for (int i = 0; i < 4; ++i) {
        float ss = oc[0][i] * oc[0][i] + oc[1][i] * oc[1][i]
                 + oc[2][i] * oc[2][i] + oc[3][i] * oc[3][i];
        ss += __shfl_xor(ss, 1); ss += __shfl_xor(ss, 2);
        ss += __shfl_xor(ss, 4); ss += __shfl_xor(ss, 8);
        float sc = 1.0f / fmaxf(sqrtf(ss), 1e-12f);
        int row = gr0 + kg * 4 + i;
        if (row < N) {
            #pragma unroll
            for (int tl = 0; tl < 4; ++tl)
                h0[(size_t)row * DD + tl * 16 + c0] = oc[tl][i] * sc;
        }
    }
}

// ---------------------------------------------------------------------------
__global__ void zero_k(int* __restrict__ p, int n)
{
    int i = blockIdx.x * blockDim.x + threadIdx.x;
    int stride = gridDim.x * blockDim.x;
    for (; i < n; i += stride) p[i] = 0;
}

// ---------------------------------------------------------------------------
// binq v2 (round-7/14, PROVEN): wave-autonomous two-pass span binner.
// Pass-1 loads are cache-filling on purpose (warm L1/L2 for pass 2).
// ---------------------------------------------------------------------------
__global__ __launch_bounds__(256)
void binq_k(const int* __restrict__ erow, const int* __restrict__ ecol, int M,
            unsigned* __restrict__ queue, int* __restrict__ qcnt,
            int cw, unsigned magic)
{
    const int wid  = blockIdx.x * 4 + (threadIdx.x >> 6);
    const int lane = threadIdx.x & 63;
    const int nw   = gridDim.x * 4;
    const int cls  = blockIdx.x & 7;

    for (int s0 = wid * SPAN; s0 < M; s0 += nw * SPAN) {
        const int e1 = min(s0 + SPAN, M);
        int tc[8] = {0, 0, 0, 0, 0, 0, 0, 0};
        for (int i = s0 + lane; i < e1; i += 64) {
            int c = ecol[i];
            unsigned p = (unsigned)(((unsigned long long)(unsigned)c * magic) >> 32);
            #pragma unroll
            for (int pp = 0; pp < 8; ++pp) tc[pp] += (p == (unsigned)pp) ? 1 : 0;
        }
        #pragma unroll
        for (int pp = 0; pp < 8; ++pp) {
            #pragma unroll
            for (int m = 1; m < 64; m <<= 1) tc[pp] += __shfl_xor(tc[pp], m);
        }
        int val = tc[0];
        #pragma unroll
        for (int pp = 1; pp < 8; ++pp) val = (lane == pp) ? tc[pp] : val;
        int base = 0;
        if (lane < 8) base = atomicAdd(&qcnt[lane * 8 + cls], val);
        int bases[8], run[8];
        #pragma unroll
        for (int pp = 0; pp < 8; ++pp) { bases[pp] = __shfl(base, pp); run[pp] = 0; }

        for (int i0 = s0; i0 < e1; i0 += 64) {
            int i = i0 + lane;
            bool act = i < e1;
            int c = act ? ecol[i] : 0;
            int r = act ? erow[i] : 0;
            unsigned p = act ? (unsigned)(((unsigned long long)(unsigned)c * magic) >> 32)
                             : 0xFFu;
            unsigned pk = (unsigned)r | ((unsigned)(c - (int)p * cw) << 17);
            #pragma unroll
            for (int pp = 0; pp < 8; ++pp) {
                unsigned long long mm = __ballot(p == (unsigned)pp);
                if (p == (unsigned)pp) {
                    int rank = __popcll(mm & ((1ull << lane) - 1ull));
                    queue[(size_t)(pp * 8 + cls) * QCAP + bases[pp] + run[pp] + rank] = pk;
                }
                run[pp] += (int)__popcll(mm);
            }
        }
    }
}

// ---------------------------------------------------------------------------
// countq v5 (round-14, measured good): ONE block per cohort. LDS hist ->
// in-block exclusive scan -> deterministic qcnt-prefix base ->
// startv[N+1] (monotonic, sentinel M) + dinv. Zero global atomics.
// ---------------------------------------------------------------------------
__global__ __launch_bounds__(1024)
void countq_k(const unsigned* __restrict__ queue, const int* __restrict__ qcnt,
              int* __restrict__ startv, float* __restrict__ dinv, int cw, int N)
{
    __shared__ int lc[CW];
    __shared__ int ts[1024];
    __shared__ int qs[64];
    const int p = blockIdx.x;
    const int tid = threadIdx.x;

    for (int i = tid; i < cw; i += 1024) lc[i] = 0;
    if (tid < 64) qs[tid] = qcnt[tid];
    __syncthreads();

    #pragma unroll 1
    for (int sq = 0; sq < 8; ++sq) {
        const int n = qs[p * 8 + sq];
        const unsigned* q = queue + (size_t)(p * 8 + sq) * QCAP;
        int i = tid;
        for (; i + 3 * 1024 < n; i += 4 * 1024) {
            unsigned e0 = q[i];
            unsigned e1 = q[i + 1024];
            unsigned e2 = q[i + 2048];
            unsigned e3 = q[i + 3072];
            atomicAdd(&lc[e0 >> 17], 1);
            atomicAdd(&lc[e1 >> 17], 1);
            atomicAdd(&lc[e2 >> 17], 1);
            atomicAdd(&lc[e3 >> 17], 1);
        }
        for (; i < n; i += 1024)
            atomicAdd(&lc[q[i] >> 17], 1);
    }
    __syncthreads();

    for (int i = tid; i < cw; i += 1024) {
        int c = lc[i];
        dinv[p * cw + i] = (c > 0) ? rsqrtf((float)c) : 0.0f;
    }
    __syncthreads();

    const int CH = (cw + 1023) / 1024;
    const int lo = tid * CH;
    const int hi = min(lo + CH, cw);
    int sum = 0;
    for (int i = lo; i < hi; ++i) { int c = lc[i]; lc[i] = sum; sum += c; }
    ts[tid] = sum;
    __syncthreads();
    #pragma unroll
    for (int o = 1; o < 1024; o <<= 1) {
        int tmp = (tid >= o) ? ts[tid - o] : 0;
        __syncthreads();
        ts[tid] += tmp;
        __syncthreads();
    }
    const int chunkBase = (tid > 0) ? ts[tid - 1] : 0;

    int base = 0;
    for (int q = 0; q < p * 8; ++q) base += qs[q];

    for (int i = lo; i < hi; ++i)
        startv[p * cw + i] = base + chunkBase + lc[i];
    if (p == gridDim.x - 1 && tid == 1023) startv[N] = base + ts[1023]; // == M
}

// ---------------------------------------------------------------------------
// fillq v4 (round-14, measured good): LDS counting sort per window.
// ---------------------------------------------------------------------------
__global__ __launch_bounds__(1024)
void fillq_k(const unsigned* __restrict__ queue, const int* __restrict__ qcnt,
             const int* __restrict__ startv, int* __restrict__ cursor,
             int* __restrict__ csr_src, int cw)
{
    __shared__ int loff[FWN + 1];
    __shared__ int lcur[FWN];
    __shared__ unsigned lbuf[FCAP];

    const int tid = threadIdx.x;
    const int p  = blockIdx.x & 7;
    const int w  = blockIdx.x >> 3;
    const int c0 = w * FWN;
    const int wn = min(FWN, cw - c0);
    const int gn0 = p * cw + c0;

    for (int i = tid; i <= wn; i += 1024) loff[i] = startv[gn0 + i];
    for (int i = tid; i < wn; i += 1024) lcur[i] = 0;
    __syncthreads();

    const int base = loff[0];
    const int span = loff[wn] - base;

    if (span <= FCAP) {
        #pragma unroll 1
        for (int sq = 0; sq < 8; ++sq) {
            const int n = qcnt[p * 8 + sq];
            const unsigned* q = queue + (size_t)(p * 8 + sq) * QCAP;
            int i = tid;
            for (; i + 3 * 1024 < n; i += 4 * 1024) {
                unsigned e0 = q[i];
                unsigned e1 = q[i + 1024];
                unsigned e2 = q[i + 2048];
                unsigned e3 = q[i + 3072];
                int cl0 = (int)(e0 >> 17) - c0;
                int cl1 = (int)(e1 >> 17) - c0;
                int cl2 = (int)(e2 >> 17) - c0;
                int cl3 = (int)(e3 >> 17) - c0;
                if ((unsigned)cl0 < (unsigned)wn)
                    lbuf[loff[cl0] - base + atomicAdd(&lcur[cl0], 1)] = e0 & 0x1FFFFu;
                if ((unsigned)cl1 < (unsigned)wn)
                    lbuf[loff[cl1] - base + atomicAdd(&lcur[cl1], 1)] = e1 & 0x1FFFFu;
                if ((unsigned)cl2 < (unsigned)wn)
                    lbuf[loff[cl2] - base + atomicAdd(&lcur[cl2], 1)] = e2 & 0x1FFFFu;
                if ((unsigned)cl3 < (unsigned)wn)
                    lbuf[loff[cl3] - base + atomicAdd(&lcur[cl3], 1)] = e3 & 0x1FFFFu;
            }
            for (; i < n; i += 1024) {
                unsigned pk = q[i];
                int cl = (int)(pk >> 17) - c0;
                if ((unsigned)cl < (unsigned)wn)
                    lbuf[loff[cl] - base + atomicAdd(&lcur[cl], 1)] = pk & 0x1FFFFu;
            }
        }
        __syncthreads();
        for (int i = tid; i < span; i += 1024)
            csr_src[base + i] = (int)lbuf[i];
    } else {
        // pathological-degree fallback (never taken for random graphs)
        #pragma unroll 1
        for (int sq = 0; sq < 8; ++sq) {
            int n = qcnt[p * 8 + sq];
            const unsigned* q = queue + (size_t)(p * 8 + sq) * QCAP;
            for (int i = tid; i < n; i += 1024) {
                unsigned pk = q[i];
                int cl = (int)(pk >> 17) - c0;
                if ((unsigned)cl < (unsigned)wn) {
                    int c = gn0 + cl;
                    int pos = startv[c] + atomicAdd(&cursor[c], 1);
                    csr_src[pos] = (int)(pk & 0x1FFFFu);
                }
            }
        }
    }
}

// ---------------------------------------------------------------------------
// mirror8[v][d] = fp8_e4m3(dinv[v] * h[v][d]) — packed u32 stores (4 dims).
// ---------------------------------------------------------------------------
__global__ __launch_bounds__(256)
void mkmir_k(const float* __restrict__ h, const float* __restrict__ dinv,
             unsigned* __restrict__ m, int N)
{
    int i = blockIdx.x * 256 + threadIdx.x;     // one u32 = 4 dims
    if (i >= N * 16) return;
    f32x4 v = ((const f32x4*)h)[i];
    float dv = dinv[i >> 4];
    unsigned u = (unsigned)f2fp8(v[0] * dv)
               | ((unsigned)f2fp8(v[1] * dv) << 8)
               | ((unsigned)f2fp8(v[2] * dv) << 16)
               | ((unsigned)f2fp8(v[3] * dv) << 24);
    m[i] = u;
}

// ---------------------------------------------------------------------------
// Propagation on fp8 mirror (round-14, measured good): 32 lanes/node,
// 8 independent gathers in flight, NT csr reads and h stores.
// hout[v] = dinv[v] * sum_r mirror[r]
// ---------------------------------------------------------------------------
__global__ __launch_bounds__(256)
void prop8_k(const unsigned char* __restrict__ min_, float* __restrict__ hout,
             unsigned short* __restrict__ mout,
             const int* __restrict__ startv,
             const int* __restrict__ csr_src, const float* __restrict__ dinv, int N)
{
    int v = blockIdx.x * 8 + (threadIdx.x >> 5);
    int l = threadIdx.x & 31;           // dim pair: dims 2l, 2l+1
    if (v >= N) return;
    int s = startv[v];
    int e = startv[v + 1];
    float dv = dinv[v];
    float a0 = 0.0f, a1 = 0.0f;
    int i = s;
    for (; i + 7 < e; i += 8) {
        int r0 = __builtin_nontemporal_load(csr_src + i + 0);
        int r1 = __builtin_nontemporal_load(csr_src + i + 1);
        int r2 = __builtin_nontemporal_load(csr_src + i + 2);
        int r3 = __builtin_nontemporal_load(csr_src + i + 3);
        int r4 = __builtin_nontemporal_load(csr_src + i + 4);
        int r5 = __builtin_nontemporal_load(csr_src + i + 5);
        int r6 = __builtin_nontemporal_load(csr_src + i + 6);
        int r7 = __builtin_nontemporal_load(csr_src + i + 7);
        unsigned short u0 = *(const unsigned short*)(min_ + (size_t)r0 * 64 + 2 * l);
        unsigned short u1 = *(const unsigned short*)(min_ + (size_t)r1 * 64 + 2 * l);
        unsigned short u2 = *(const unsigned short*)(min_ + (size_t)r2 * 64 + 2 * l);
        unsigned short u3 = *(const unsigned short*)(min_ + (size_t)r3 * 64 + 2 * l);
        unsigned short u4 = *(const unsigned short*)(min_ + (size_t)r4 * 64 + 2 * l);
        unsigned short u5 = *(const unsigned short*)(min_ + (size_t)r5 * 64 + 2 * l);
        unsigned short u6 = *(const unsigned short*)(min_ + (size_t)r6 * 64 + 2 * l);
        unsigned short u7 = *(const unsigned short*)(min_ + (size_t)r7 * 64 + 2 * l);
        a0 += fp82f((unsigned char)(u0 & 255)) + fp82f((unsigned char)(u1 & 255))
            + fp82f((unsigned char)(u2 & 255)) + fp82f((unsigned char)(u3 & 255))
            + fp82f((unsigned char)(u4 & 255)) + fp82f((unsigned char)(u5 & 255))
            + fp82f((unsigned char)(u6 & 255)) + fp82f((unsigned char)(u7 & 255));
        a1 += fp82f((unsigned char)(u0 >> 8)) + fp82f((unsigned char)(u1 >> 8))
            + fp82f((unsigned char)(u2 >> 8)) + fp82f((unsigned char)(u3 >> 8))
            + fp82f((unsigned char)(u4 >> 8)) + fp82f((unsigned char)(u5 >> 8))
            + fp82f((unsigned char)(u6 >> 8)) + fp82f((unsigned char)(u7 >> 8));
    }
    for (; i < e; ++i) {
        int r = __builtin_nontemporal_load(csr_src + i);
        unsigned short u = *(const unsigned short*)(min_ + (size_t)r * 64 + 2 * l);
        a0 += fp82f((unsigned char)(u & 255));
        a1 += fp82f((unsigned char)(u >> 8));
    }
    float r0 = dv * a0, r1 = dv * a1;
    f32x2 st = {r0, r1};
    __builtin_nontemporal_store(st, (f32x2*)(hout + (size_t)v * DD + 2 * l));
    if (mout) {
        unsigned short mv = (unsigned short)f2fp8(dv * r0)
                          | ((unsigned short)f2fp8(dv * r1) << 8);
        mout[(size_t)v * 32 + l] = mv;
    }
}

// ---------------------------------------------------------------------------
extern "C" void kernel_launch(void* const* d_in, const int* in_sizes, int n_in,
                              void* d_out, int out_size, void* d_ws, size_t ws_size,
                              hipStream_t stream)
{
    const float* x     = (const float*)d_in[0];
    const int*   ei    = (const int*)  d_in[1];
    const float* W1    = (const float*)d_in[2];
    const float* b1    = (const float*)d_in[3];
    const float* gamma = (const float*)d_in[4];
    const float* beta  = (const float*)d_in[5];
    const float* W2    = (const float*)d_in[6];
    const float* b2    = (const float*)d_in[7];
    float* out = (float*)d_out;

    const int N = in_sizes[0] / F_IN;       // 100000
    const int M = in_sizes[1] / 2;          // 3300000
    const int cw = (N + 7) / 8;             // 12500
    const unsigned magic = (unsigned)((0x100000000ULL + cw - 1) / cw);
    const int* erow = ei;
    const int* ecol = ei + M;

    // workspace layout (ints)
    int* wsI = (int*)d_ws;
    int*   cursor  = wsI;                               // N (fillq fallback)
    int*   qcnt    = wsI + N;                           // 64 (+4 pad)
    int*   startv  = wsI + N + 68;                      // N+1
    float* dinv    = (float*)(wsI + 2 * N + 70);        // N
    h16*   w1t     = (h16*)(wsI + 3 * N + 70);          // 8192 ints
    h16*   w2t     = (h16*)(wsI + 3 * N + 70 + 8192);   // 1024 ints
    int*   csr_src = wsI + 3 * N + 70 + 9216;           // M
    unsigned* queue = (unsigned*)(csr_src + M);         // 64*QCAP u32 (25.6MB)
    unsigned char* mir0 = (unsigned char*)queue;        // overlays queue (dead after fillq)
    unsigned char* mir1 = mir0 + (size_t)N * 64;        // 6.4MB each

    // zero cursor + qcnt
    zero_k<<<512, 256, 0, stream>>>(wsI, N + 68);
    prep_k<<<(32 * 512 + 64 * 32 + 255) / 256, 256, 0, stream>>>(W1, W2, w1t, w2t);

    encoder_k<<<(N + 63) / 64, 256, 0, stream>>>(x, w1t, b1, gamma, beta, w2t, b2, out, N);

    binq_k<<<256, 256, 0, stream>>>(erow, ecol, M, queue, qcnt, cw, magic);

    countq_k<<<8, 1024, 0, stream>>>(queue, qcnt, startv, dinv, cw, N);

    const int NWF = (cw + FWN - 1) / FWN;   // 28
    fillq_k<<<NWF * 8, 1024, 0, stream>>>(queue, qcnt, startv, cursor, csr_src, cw);

    float* h0 = out;
    float* h1 = out + (size_t)N * DD;
    float* h2 = out + 2 * (size_t)N * DD;

    mkmir_k<<<(N * 16 + 255) / 256, 256, 0, stream>>>(h0, dinv, (unsigned*)mir0, N);

    prop8_k<<<(N + 7) / 8, 256, 0, stream>>>(mir0, h1, (unsigned short*)mir1,
                                             startv, csr_src, dinv, N);
    prop8_k<<<(N + 7) / 8, 256, 0, stream>>>(mir1, h2, (unsigned short*)nullptr,
                                             startv, csr_src, dinv, N);
}